// Round 10
// baseline (707.187 us; speedup 1.0000x reference)
//
#include <hip/hip_runtime.h>
#include <math.h>

#define Bg   64
#define Mg   100
#define Ng   6400
#define Eg   102400
#define Hh   4
#define Dd   512
#define HDd  2048
#define EMBd 768
#define IMGd 1024
#define EPSc 1e-5f

typedef __bf16 bf16x8 __attribute__((ext_vector_type(8)));
typedef float  f32x4  __attribute__((ext_vector_type(4)));

#define SBAR __builtin_amdgcn_sched_barrier(0)
#define WBAR __builtin_amdgcn_s_barrier()

__device__ __forceinline__ float eluf(float x) { return x > 0.f ? x : expm1f(x); }

__device__ __forceinline__ unsigned short f2bf(float x) {
    unsigned int u = __builtin_bit_cast(unsigned int, x);
    u += 0x7FFFu + ((u >> 16) & 1u);
    return (unsigned short)(u >> 16);
}
__device__ __forceinline__ float bf2f(unsigned short s) {
    return __builtin_bit_cast(float, ((unsigned int)s) << 16);
}

__device__ __forceinline__ void gld16(const void* g, void* l) {
    __builtin_amdgcn_global_load_lds(
        (const __attribute__((address_space(1))) void*)g,
        (__attribute__((address_space(3))) void*)l, 16, 0, 0);
}

// ---------------------------------------------------------------------------
// bf16 MFMA GEMM, 256x256 tile, 8-phase pipeline (T2+T3+T4+T5), R6 sync form.
// Requires M%256==0, N%256==0, K%128==0.  C = act(A[M,K] @ W[N,K]^T + b)
// ---------------------------------------------------------------------------
__global__ __launch_bounds__(512, 2)
void gemm_bf16_256(const unsigned short* __restrict__ A,
                   const unsigned short* __restrict__ W,
                   const float* __restrict__ bias, void* __restrict__ C,
                   int M, int N, int K, int act, int outbf)
{
    __shared__ __align__(16) unsigned short As[2][256 * 64];
    __shared__ __align__(16) unsigned short Bs[2][256 * 64];

    const int tid  = threadIdx.x;
    const int lane = tid & 63, wid = tid >> 6;
    const int wm = wid >> 2, wn = wid & 3;
    const int bm = blockIdx.y * 256, bn = blockIdx.x * 256;
    const int fl = lane & 15;                 // fragment row within 16
    const int fsl = lane >> 4;                // logical 16B slot of fragment

    f32x4 acc[8][4] = {};
    bf16x8 a_[4][2];
    bf16x8 b_[2][2][2];

    const int NT = K >> 6;                    // 64-wide K-tiles (even count)

    const int srow0 = tid >> 3;
    const int scol  = (((tid & 7) ^ ((tid >> 3) & 7)) << 3);
    const unsigned short* pAs = A + (size_t)(bm + srow0) * K + scol;
    const unsigned short* pBs = W + (size_t)(bn + srow0) * K + scol;
    const size_t K64 = (size_t)K * 64, K128 = (size_t)K * 128;

#define STGA(kt, h, d)                                                        \
    do {                                                                      \
        gld16(pAs + (h) * K128 + ((kt) << 6),                                 \
              (char*)As[d] + (h) * 16384 + wid * 1024);                       \
        gld16(pAs + (h) * K128 + K64 + ((kt) << 6),                           \
              (char*)As[d] + (h) * 16384 + 8192 + wid * 1024);                \
    } while (0)
#define STGB(kt, h, d)                                                        \
    do {                                                                      \
        gld16(pBs + (h) * K128 + ((kt) << 6),                                 \
              (char*)Bs[d] + (h) * 16384 + wid * 1024);                       \
        gld16(pBs + (h) * K128 + K64 + ((kt) << 6),                           \
              (char*)Bs[d] + (h) * 16384 + 8192 + wid * 1024);                \
    } while (0)

#define LDA(qm, d)                                                            \
    _Pragma("unroll") for (int i = 0; i < 4; ++i)                             \
    _Pragma("unroll") for (int kk = 0; kk < 2; ++kk) {                        \
        int r_  = wm * 128 + (qm) * 64 + i * 16 + fl;                         \
        int sl_ = ((kk << 2) + fsl) ^ (fl & 7);                               \
        a_[i][kk] = *(const bf16x8*)((const char*)As[d] + r_ * 128 + (sl_ << 4)); \
    }
#define LDB(qn, d)                                                            \
    _Pragma("unroll") for (int j = 0; j < 2; ++j)                             \
    _Pragma("unroll") for (int kk = 0; kk < 2; ++kk) {                        \
        int r_  = wn * 64 + (qn) * 32 + j * 16 + fl;                          \
        int sl_ = ((kk << 2) + fsl) ^ (fl & 7);                               \
        b_[qn][j][kk] = *(const bf16x8*)((const char*)Bs[d] + r_ * 128 + (sl_ << 4)); \
    }
#define PHMM(qm, qn)                                                          \
    do {                                                                      \
        WBAR;                                                                 \
        __builtin_amdgcn_s_setprio(1);                                        \
        _Pragma("unroll") for (int kk = 0; kk < 2; ++kk)                      \
        _Pragma("unroll") for (int i = 0; i < 4; ++i)                         \
        _Pragma("unroll") for (int j = 0; j < 2; ++j)                         \
            acc[(qm) * 4 + i][(qn) * 2 + j] =                                 \
                __builtin_amdgcn_mfma_f32_16x16x32_bf16(                      \
                    a_[i][kk], b_[qn][j][kk],                                 \
                    acc[(qm) * 4 + i][(qn) * 2 + j], 0, 0, 0);                \
        __builtin_amdgcn_s_setprio(0);                                        \
        WBAR;                                                                 \
    } while (0)

    // ---- prologue: B(0), A(0), B(1); drain tile 0, leave B(1) in flight ----
    STGB(0, 0, 0); STGB(0, 1, 0);
    STGA(0, 0, 0); STGA(0, 1, 0);
    STGB(1, 0, 1); STGB(1, 1, 1);
    asm volatile("s_waitcnt vmcnt(4)" ::: "memory");
    WBAR;

    for (int j = 0; j < (NT >> 1); ++j) {
        const int O = 2 * j + 1;
        const int g1 = (2 * j + 2 < NT), g2 = (2 * j + 3 < NT);

        LDA(0, 0); LDB(0, 0);
        STGA(O, 0, 1);
        PHMM(0, 0);

        LDB(1, 0);
        STGA(O, 1, 1);
        PHMM(0, 1);

        LDA(1, 0);
        if (g1) STGB(2 * j + 2, 0, 0);
        PHMM(1, 0);

        if (g1) STGB(2 * j + 2, 1, 0);
        if (g1) { asm volatile("s_waitcnt vmcnt(4)" ::: "memory"); }
        else    { asm volatile("s_waitcnt vmcnt(0)" ::: "memory"); }
        PHMM(1, 1);

        LDA(0, 1); LDB(0, 1);
        if (g1) STGA(2 * j + 2, 0, 0);
        PHMM(0, 0);

        LDB(1, 1);
        if (g1) STGA(2 * j + 2, 1, 0);
        PHMM(0, 1);

        LDA(1, 1);
        if (g2) STGB(2 * j + 3, 0, 1);
        PHMM(1, 0);

        if (g2) STGB(2 * j + 3, 1, 1);
        if (g1) { asm volatile("s_waitcnt vmcnt(4)" ::: "memory"); }
        else    { asm volatile("s_waitcnt vmcnt(0)" ::: "memory"); }
        PHMM(1, 1);
    }

#undef STGA
#undef STGB
#undef LDA
#undef LDB
#undef PHMM

    // ---- epilogue ----
    const int crow0 = bm + wm * 128 + ((lane >> 4) << 2);
    const int ccol0 = bn + wn * 64 + fl;
#pragma unroll
    for (int fr = 0; fr < 8; ++fr) {
#pragma unroll
        for (int fc = 0; fc < 4; ++fc) {
            int col = ccol0 + fc * 16;
            float bv = bias ? bias[col] : 0.f;
#pragma unroll
            for (int rr = 0; rr < 4; ++rr) {
                int row = crow0 + fr * 16 + rr;
                float v = acc[fr][fc][rr] + bv;
                if (act) v = eluf(v);
                if (outbf) ((unsigned short*)C)[(size_t)row * N + col] = f2bf(v);
                else       ((float*)C)[(size_t)row * N + col] = v;
            }
        }
    }
}

// ---------------------------------------------------------------------------
// bf16 MFMA GEMM, 64x64 tile. R10: K-step 32 -> 64 (8 MFMA/wave per barrier
// pair instead of 4 -> barrier overhead halved), 128B LDS rows with the
// proven 3-bit slot swizzle from the 256^2 kernel (0 conflicts measured).
// depth-2 counted-vmcnt pipeline (STAGE=4 loads -> steady wait vmcnt(4)).
// Optional fused row-BN (p = row%100) applied after act.
// Requires K%64==0 (512, 2048); N guarded (480 ok).
// ---------------------------------------------------------------------------
__global__ __launch_bounds__(256)
void gemm_bf16_t64(const unsigned short* __restrict__ A,
                   const unsigned short* __restrict__ W,
                   const float* __restrict__ bias, void* __restrict__ C,
                   int M, int N, int K, int act, int outbf,
                   const float* __restrict__ rg, const float* __restrict__ rb,
                   const float* __restrict__ rm, const float* __restrict__ rv)
{
    __shared__ __align__(16) unsigned short As[2][64 * 64];
    __shared__ __align__(16) unsigned short Bs[2][64 * 64];
    const int tid  = threadIdx.x;
    const int lane = tid & 63, wid = tid >> 6;
    const int bm = blockIdx.y * 64, bn = blockIdx.x * 64;
    const int wm = (wid >> 1) * 32, wn = (wid & 1) * 32;

    f32x4 acc[2][2] = {};
    const int fl  = lane & 15;
    const int fsl = lane >> 4;

    // staging: round h covers rows h*32 + (tid>>3), slot tid&7 (linear LDS);
    // source pre-swizzled so read-side slot ^= (row&7) sees logical data.
    const int srow0 = tid >> 3;                               // 0..31
    const int scol  = (((tid & 7) ^ ((tid >> 3) & 7)) << 3);
    const unsigned short* gA0 = A + (size_t)(bm + srow0) * K + scol;
    const unsigned short* gA1 = A + (size_t)(bm + 32 + srow0) * K + scol;
    int rb0 = bn + srow0;      if (rb0 >= N) rb0 = N - 1;
    int rb1 = bn + 32 + srow0; if (rb1 >= N) rb1 = N - 1;
    const unsigned short* gB0 = W + (size_t)rb0 * K + scol;
    const unsigned short* gB1 = W + (size_t)rb1 * K + scol;

    const int nt = K >> 6;

#define STG64(t, b)                                                     \
    do {                                                                \
        const int k0_ = (t) << 6;                                       \
        gld16(gA0 + k0_, (char*)As[b] + wid * 1024);                    \
        gld16(gA1 + k0_, (char*)As[b] + 4096 + wid * 1024);             \
        gld16(gB0 + k0_, (char*)Bs[b] + wid * 1024);                    \
        gld16(gB1 + k0_, (char*)Bs[b] + 4096 + wid * 1024);             \
    } while (0)

    STG64(0, 0);
    if (nt > 1) STG64(1, 1);

    for (int t = 0; t < nt; ++t) {
        const int bi = t & 1;
        if (t + 1 < nt) { asm volatile("s_waitcnt vmcnt(4)" ::: "memory"); }
        else            { asm volatile("s_waitcnt vmcnt(0)" ::: "memory"); }
        WBAR;

        bf16x8 a_[2][2], b_[2][2];
#pragma unroll
        for (int i = 0; i < 2; ++i)
#pragma unroll
            for (int kk = 0; kk < 2; ++kk) {
                int ra_ = wm + i * 16 + fl;
                int rbq = wn + i * 16 + fl;
                int sl_ = ((kk << 2) + fsl) ^ (fl & 7);
                a_[i][kk] = *(const bf16x8*)((const char*)As[bi] + ra_ * 128 + (sl_ << 4));
                b_[i][kk] = *(const bf16x8*)((const char*)Bs[bi] + rbq * 128 + (sl_ << 4));
            }
#pragma unroll
        for (int kk = 0; kk < 2; ++kk)
#pragma unroll
            for (int i = 0; i < 2; ++i)
#pragma unroll
                for (int j = 0; j < 2; ++j)
                    acc[i][j] = __builtin_amdgcn_mfma_f32_16x16x32_bf16(
                        a_[i][kk], b_[j][kk], acc[i][j], 0, 0, 0);

        WBAR;
        if (t + 2 < nt) STG64(t + 2, bi);
    }
#undef STG64

    const int crow0 = bm + wm + ((lane >> 4) << 2);
    const int ccol0 = bn + wn + (lane & 15);
#pragma unroll
    for (int mi = 0; mi < 2; ++mi) {
#pragma unroll
        for (int ni = 0; ni < 2; ++ni) {
            int col = ccol0 + ni * 16;
            if (col >= N) continue;
            float bv = bias ? bias[col] : 0.f;
#pragma unroll
            for (int r = 0; r < 4; ++r) {
                int row = crow0 + mi * 16 + r;
                float v = acc[mi][ni][r] + bv;
                if (act) v = eluf(v);
                if (rg) {
                    int prow = row % Mg;
                    float sc = rsqrtf(rv[prow] + EPSc) * rg[prow];
                    v = v * sc + (rb[prow] - rm[prow] * sc);
                }
                if (outbf) ((unsigned short*)C)[(size_t)row * N + col] = f2bf(v);
                else       ((float*)C)[(size_t)row * N + col] = v;
            }
        }
    }
}

// ---------------------------------------------------------------------------
// BN scale/shift precompute: sc = g*rsqrt(v+eps), sh = b - m*sc
// ---------------------------------------------------------------------------
__global__ void bn_prep(const float* __restrict__ g, const float* __restrict__ b,
                        const float* __restrict__ m, const float* __restrict__ v,
                        float* __restrict__ sc, float* __restrict__ sh, int K)
{
    int i = blockIdx.x * 256 + threadIdx.x;
    if (i < K) {
        float s = rsqrtf(v[i] + EPSc) * g[i];
        sc[i] = s;
        sh[i] = b[i] - m[i] * s;
    }
}

// ---------------------------------------------------------------------------
// Branch GEMV: Y[64,N] = elu((X*sc+sh) @ Wt^T + bias). One wave per output
// element, 4 outputs (same row) per block -> 64*N/4 blocks (full occupancy).
// Requires K % 256 == 0 (K=1024 img, K=768 text).
// ---------------------------------------------------------------------------
__global__ __launch_bounds__(256)
void branch_gemv(const float* __restrict__ X, const float* __restrict__ Wt,
                 const float* __restrict__ bias,
                 const float* __restrict__ sc, const float* __restrict__ sh,
                 float* __restrict__ Y, int N, int K)
{
    const int wid = threadIdx.x >> 6, lane = threadIdx.x & 63;
    const int nb = N >> 2;
    const int r  = blockIdx.x / nb;
    const int n  = (blockIdx.x % nb) * 4 + wid;
    const float* xp = X + (size_t)r * K;
    const float* wp = Wt + (size_t)n * K;
    float s = 0.f;
    for (int k = lane * 4; k < K; k += 256) {
        float4 x  = *(const float4*)(xp + k);
        float4 w  = *(const float4*)(wp + k);
        float4 cc = *(const float4*)(sc + k);
        float4 hh = *(const float4*)(sh + k);
        s += (x.x * cc.x + hh.x) * w.x + (x.y * cc.y + hh.y) * w.y
           + (x.z * cc.z + hh.z) * w.z + (x.w * cc.w + hh.w) * w.w;
    }
#pragma unroll
    for (int o = 32; o > 0; o >>= 1) s += __shfl_down(s, o, 64);
    if (lane == 0) Y[(size_t)r * N + n] = eluf(s + bias[n]);
}

// ---------------------------------------------------------------------------
// Merged fp32 -> bf16 conversion for 6 arrays (4-wide; all sizes %4 == 0).
// ---------------------------------------------------------------------------
struct CvtPack {
    const float* s[6];
    unsigned short* d[6];
    int n4[6];
};

__global__ void cvt_all(CvtPack p, int total4)
{
    int i = blockIdx.x * 256 + threadIdx.x;
    if (i >= total4) return;
#pragma unroll
    for (int k = 0; k < 6; ++k) {
        if (i < p.n4[k]) {
            float4 v = ((const float4*)p.s[k])[i];
            ushort4 o;
            o.x = f2bf(v.x); o.y = f2bf(v.y); o.z = f2bf(v.z); o.w = f2bf(v.w);
            ((ushort4*)p.d[k])[i] = o;
            return;
        }
        i -= p.n4[k];
    }
}

// ---------------------------------------------------------------------------
// CSR build by dst
// ---------------------------------------------------------------------------
__global__ void zero_i32(int* __restrict__ p, int n)
{
    int i = blockIdx.x * 256 + threadIdx.x;
    if (i < n) p[i] = 0;
}

__global__ void count_dst(const int* __restrict__ dst, int* __restrict__ counts, int E)
{
    int i = blockIdx.x * 256 + threadIdx.x;
    if (i < E) atomicAdd(&counts[dst[i]], 1);
}

__global__ __launch_bounds__(1024)
void scan_excl(const int* __restrict__ counts, int* __restrict__ offs,
               int* __restrict__ cursor, int n)
{
    __shared__ int sm[1024];
    __shared__ int carry;
    if (threadIdx.x == 0) carry = 0;
    __syncthreads();
    for (int base = 0; base < n; base += 1024) {
        int i = base + (int)threadIdx.x;
        int v = (i < n) ? counts[i] : 0;
        sm[threadIdx.x] = v;
        __syncthreads();
        for (int o = 1; o < 1024; o <<= 1) {
            int t = (threadIdx.x >= (unsigned)o) ? sm[threadIdx.x - o] : 0;
            __syncthreads();
            sm[threadIdx.x] += t;
            __syncthreads();
        }
        int incl = sm[threadIdx.x];
        int myc = carry;
        if (i < n) {
            int ex = myc + incl - v;
            offs[i] = ex;
            cursor[i] = ex;
        }
        __syncthreads();
        if (threadIdx.x == 1023) carry = myc + sm[1023];
        __syncthreads();
    }
    if (threadIdx.x == 0) offs[n] = carry;
}

__global__ void scatter_edges(const int* __restrict__ dst, int* __restrict__ cursor,
                              int* __restrict__ eid, int E)
{
    int i = blockIdx.x * 256 + threadIdx.x;
    if (i < E) {
        int p = atomicAdd(&cursor[dst[i]], 1);
        eid[p] = i;
    }
}

// ---------------------------------------------------------------------------
// el/er: one wave per (n,h); lane owns 8 consecutive dims -> one 16B load.
// ---------------------------------------------------------------------------
__global__ __launch_bounds__(256)
void elr_kernel(const unsigned short* __restrict__ Hm, const float* __restrict__ al,
                const float* __restrict__ ar, float* __restrict__ el,
                float* __restrict__ er)
{
    int wid = threadIdx.x >> 6, lane = threadIdx.x & 63;
    int g = (blockIdx.x << 2) + wid;
    int n = g >> 2, h = g & 3;
    const unsigned short* hp = Hm + ((size_t)n << 11) + (h << 9) + (lane << 3);
    const float* alp = al + (h << 9) + (lane << 3);
    const float* arp = ar + (h << 9) + (lane << 3);
    ushort4 x0 = *(const ushort4*)hp;
    ushort4 x1 = *(const ushort4*)(hp + 4);
    float4 l0 = *(const float4*)alp, l1 = *(const float4*)(alp + 4);
    float4 r0 = *(const float4*)arp, r1 = *(const float4*)(arp + 4);
    float a0 = bf2f(x0.x), a1 = bf2f(x0.y), a2 = bf2f(x0.z), a3 = bf2f(x0.w);
    float a4 = bf2f(x1.x), a5 = bf2f(x1.y), a6 = bf2f(x1.z), a7 = bf2f(x1.w);
    float se = a0*l0.x + a1*l0.y + a2*l0.z + a3*l0.w + a4*l1.x + a5*l1.y + a6*l1.z + a7*l1.w;
    float sr = a0*r0.x + a1*r0.y + a2*r0.z + a3*r0.w + a4*r1.x + a5*r1.y + a6*r1.z + a7*r1.w;
#pragma unroll
    for (int o = 32; o > 0; o >>= 1) {
        se += __shfl_down(se, o, 64);
        sr += __shfl_down(sr, o, 64);
    }
    if (lane == 0) { el[g] = se; er[g] = sr; }
}

// ---------------------------------------------------------------------------
// GAT aggregation: one block per dst node. Thread owns dims [4t,4t+4) and
// [1024+4t, 1024+4t+4) -> two 8B loads per edge, 2 heads per thread.
// ---------------------------------------------------------------------------
__global__ __launch_bounds__(256)
void gat_agg(const unsigned short* __restrict__ Hm, const float* __restrict__ el,
             const float* __restrict__ er, const int* __restrict__ src,
             const int* __restrict__ offs, const int* __restrict__ eid,
             const float* __restrict__ bias, unsigned short* __restrict__ out)
{
    int n = blockIdx.x;
    int tid = threadIdx.x;
    int beg = offs[n], end = offs[n + 1];
    int deg = end - beg;
    const int b0 = tid << 2;          // dims 0..1023
    const int b1 = 1024 + (tid << 2); // dims 1024..2047
    const int h0 = tid >> 7;          // head of b0 (0 or 1)
    const int h1 = h0 + 2;            // head of b1

    if (deg == 0) {
#pragma unroll
        for (int j = 0; j < 4; ++j) {
            out[((size_t)n << 11) + b0 + j] = f2bf(bias[b0 + j]);
            out[((size_t)n << 11) + b1 + j] = f2bf(bias[b1 + j]);
        }
        return;
    }

    __shared__ float m_sh[4], s_sh[4], al_sh[4];
    __shared__ int   src_sh[128];
    __shared__ float logit_sh[512];
    __shared__ float w_sh[512];

    if (tid < 4) { m_sh[tid] = -INFINITY; s_sh[tid] = 0.f; }
    float acc[8] = {0.f,0.f,0.f,0.f,0.f,0.f,0.f,0.f};
    __syncthreads();

    for (int c0 = 0; c0 < deg; c0 += 128) {
        int cnt = min(128, deg - c0);
        for (int i = tid; i < cnt; i += 256) src_sh[i] = src[eid[beg + c0 + i]];
        __syncthreads();
        for (int idx = tid; idx < (cnt << 2); idx += 256) {
            int i = idx >> 2, h = idx & 3;
            float x = el[(src_sh[i] << 2) + h] + er[(n << 2) + h];
            logit_sh[idx] = x > 0.f ? x : 0.2f * x;
        }
        __syncthreads();
        if (tid < 4) {
            float cm = -INFINITY;
            for (int i = 0; i < cnt; ++i) cm = fmaxf(cm, logit_sh[(i << 2) + tid]);
            float mn = fmaxf(m_sh[tid], cm);
            al_sh[tid] = expf(m_sh[tid] - mn);
            m_sh[tid] = mn;
        }
        __syncthreads();
        for (int idx = tid; idx < (cnt << 2); idx += 256)
            w_sh[idx] = expf(logit_sh[idx] - m_sh[idx & 3]);
        __syncthreads();
        if (tid < 4) {
            float cs = 0.f;
            for (int i = 0; i < cnt; ++i) cs += w_sh[(i << 2) + tid];
            s_sh[tid] = s_sh[tid] * al_sh[tid] + cs;
        }
        float r0 = al_sh[h0], r1 = al_sh[h1];
        acc[0] *= r0; acc[1] *= r0; acc[2] *= r0; acc[3] *= r0;
        acc[4] *= r1; acc[5] *= r1; acc[6] *= r1; acc[7] *= r1;
        for (int i = 0; i < cnt; ++i) {
            const unsigned short* hp = Hm + ((size_t)src_sh[i] << 11);
            ushort4 a = *(const ushort4*)(hp + b0);
            ushort4 b = *(const ushort4*)(hp + b1);
            float w0 = w_sh[(i << 2) + h0], w1 = w_sh[(i << 2) + h1];
            acc[0] += w0 * bf2f(a.x); acc[1] += w0 * bf2f(a.y);
            acc[2] += w0 * bf2f(a.z); acc[3] += w0 * bf2f(a.w);
            acc[4] += w1 * bf2f(b.x); acc[5] += w1 * bf2f(b.y);
            acc[6] += w1 * bf2f(b.z); acc[7] += w1 * bf2f(b.w);
        }
        __syncthreads();
    }

    float is0 = 1.f / s_sh[h0], is1 = 1.f / s_sh[h1];
#pragma unroll
    for (int j = 0; j < 4; ++j) {
        out[((size_t)n << 11) + b0 + j] = f2bf(acc[j] * is0 + bias[b0 + j]);
        out[((size_t)n << 11) + b1 + j] = f2bf(acc[4 + j] * is1 + bias[b1 + j]);
    }
}

// ---------------------------------------------------------------------------
// mean over 100 nodes of concat([hg 480, pos-branch 32]) -> hf[64,512].
// pos branch computed inline (p = n%100 = m within a graph).
// ---------------------------------------------------------------------------
__global__ void mean_kernel(const float* __restrict__ hg, const float* __restrict__ pos,
                            const float* __restrict__ bg, const float* __restrict__ bb_,
                            const float* __restrict__ bm_, const float* __restrict__ bv_,
                            const float* __restrict__ W, const float* __restrict__ bias,
                            float* __restrict__ hf)
{
    int i = blockIdx.x * 256 + threadIdx.x;   // < 64*512
    if (i >= Bg * Dd) return;
    int bb = i >> 9, c = i & 511;
    float s = 0.f;
    if (c < 480) {
        const float* p = hg + (size_t)bb * Mg * 480 + c;
        for (int mm = 0; mm < Mg; ++mm) s += p[mm * 480];
    } else {
        int o = c - 480;
        float w0 = W[(o << 2) + 0], w1 = W[(o << 2) + 1];
        float w2 = W[(o << 2) + 2], w3 = W[(o << 2) + 3];
        float bo = bias[o];
        const float* pp = pos + (size_t)bb * Mg * 4;
        for (int mm = 0; mm < Mg; ++mm) {
            float sc = rsqrtf(bv_[mm] + EPSc) * bg[mm];
            float sh = bb_[mm] - bm_[mm] * sc;
            float a = bo + (pp[mm*4+0]*sc+sh)*w0 + (pp[mm*4+1]*sc+sh)*w1
                         + (pp[mm*4+2]*sc+sh)*w2 + (pp[mm*4+3]*sc+sh)*w3;
            s += eluf(a);
        }
    }
    hf[i] = s * 0.01f;
}

__global__ __launch_bounds__(256)
void final_kernel(const float* __restrict__ x, const float* __restrict__ hf,
                  const float* __restrict__ ft, const float* __restrict__ g,
                  const float* __restrict__ b, const float* __restrict__ m,
                  const float* __restrict__ v, const float* __restrict__ W,
                  const float* __restrict__ bias, float* __restrict__ out)
{
    int bb = blockIdx.x;
    int tid = threadIdx.x;
    float a0 = 0.f, a1 = 0.f;
    for (int c = tid; c < 1536; c += 256) {
        float xv = (c < 512) ? x[bb * 512 + c]
                 : (c < 1024) ? hf[bb * 512 + (c - 512)]
                              : ft[bb * 512 + (c - 1024)];
        float z = (xv - m[c]) * rsqrtf(v[c] + EPSc) * g[c] + b[c];
        a0 += z * W[c];
        a1 += z * W[1536 + c];
    }
    __shared__ float r0[256], r1[256];
    r0[tid] = a0; r1[tid] = a1;
    __syncthreads();
    for (int o = 128; o > 0; o >>= 1) {
        if (tid < o) { r0[tid] += r0[tid + o]; r1[tid] += r1[tid + o]; }
        __syncthreads();
    }
    if (tid == 0) {
        out[bb * 2 + 0] = r0[0] + bias[0];
        out[bb * 2 + 1] = r1[0] + bias[1];
    }
}

// ---------------------------------------------------------------------------
extern "C" void kernel_launch(void* const* d_in, const int* in_sizes, int n_in,
                              void* d_out, int out_size, void* d_ws, size_t ws_size,
                              hipStream_t stream)
{
    (void)in_sizes; (void)n_in; (void)out_size; (void)ws_size;

    const float* img   = (const float*)d_in[0];
    const float* ftxt  = (const float*)d_in[1];
    const float* unixe = (const float*)d_in[2];
    const float* pos   = (const float*)d_in[3];
    const int*   src   = (const int*)  d_in[4];
    const int*   dst   = (const int*)  d_in[5];
    const float* g1W   = (const float*)d_in[6];
    const float* g1al  = (const float*)d_in[7];
    const float* g1ar  = (const float*)d_in[8];
    const float* g1b   = (const float*)d_in[9];
    const float* g2W   = (const float*)d_in[10];
    const float* g2al  = (const float*)d_in[11];
    const float* g2ar  = (const float*)d_in[12];
    const float* g2b   = (const float*)d_in[13];
    const float* fcW   = (const float*)d_in[14];
    const float* fcb   = (const float*)d_in[15];
    const float* hidW  = (const float*)d_in[16];
    const float* hidb  = (const float*)d_in[17];
    const float* btg   = (const float*)d_in[18];
    const float* btb   = (const float*)d_in[19];
    const float* btm   = (const float*)d_in[20];
    const float* btv   = (const float*)d_in[21];
    const float* ftW   = (const float*)d_in[22];
    const float* ftbi  = (const float*)d_in[23];
    const float* swg   = (const float*)d_in[24];
    const float* swb   = (const float*)d_in[25];
    const float* swm   = (const float*)d_in[26];
    const float* swv   = (const float*)d_in[27];
    const float* swW   = (const float*)d_in[28];
    const float* swbi  = (const float*)d_in[29];
    const float* bgg   = (const float*)d_in[30];
    const float* bgb   = (const float*)d_in[31];
    const float* bgm   = (const float*)d_in[32];
    const float* bgv   = (const float*)d_in[33];
    const float* fgW   = (const float*)d_in[34];
    const float* fgb   = (const float*)d_in[35];
    const float* bbgp  = (const float*)d_in[36];
    const float* bbbp  = (const float*)d_in[37];
    const float* bbmp  = (const float*)d_in[38];
    const float* bbvp  = (const float*)d_in[39];
    const float* fbW   = (const float*)d_in[40];
    const float* fbb   = (const float*)d_in[41];
    const float* fng   = (const float*)d_in[42];
    const float* fnb   = (const float*)d_in[43];
    const float* fnm   = (const float*)d_in[44];
    const float* fnv   = (const float*)d_in[45];
    const float* fiW   = (const float*)d_in[46];
    const float* fib   = (const float*)d_in[47];
    float* out = (float*)d_out;

    // ---- workspace layout ----
    char* p = (char*)d_ws;
    unsigned short* fA  = (unsigned short*)p; p += (size_t)Ng * HDd * 2;
    unsigned short* fB  = (unsigned short*)p; p += (size_t)Ng * HDd * 2;
    unsigned short* fC  = (unsigned short*)p; p += (size_t)Ng * Dd * 2;
    unsigned short* fD  = (unsigned short*)p; p += (size_t)Ng * Dd * 2;
    float*          fE  = (float*)p;          p += (size_t)Ng * 480 * 4;
    float*          el  = (float*)p;          p += (size_t)Ng * Hh * 4;
    float*          er  = (float*)p;          p += (size_t)Ng * Hh * 4;
    float*          xb  = (float*)p;          p += (size_t)Bg * Dd * 4;
    float*          ftb = (float*)p;          p += (size_t)Bg * Dd * 4;
    float*          hf  = (float*)p;          p += (size_t)Bg * Dd * 4;
    float*          sci = (float*)p;          p += (size_t)IMGd * 4;
    float*          shi = (float*)p;          p += (size_t)IMGd * 4;
    float*          sct = (float*)p;          p += (size_t)EMBd * 4;
    float*          sht = (float*)p;          p += (size_t)EMBd * 4;
    unsigned short* ubf = (unsigned short*)p; p += (size_t)Ng * EMBd * 2;
    unsigned short* wg1 = (unsigned short*)p; p += (size_t)HDd * EMBd * 2;
    unsigned short* wg2 = (unsigned short*)p; p += (size_t)HDd * HDd * 2;
    unsigned short* wfc = (unsigned short*)p; p += (size_t)Dd * HDd * 2;
    unsigned short* whid= (unsigned short*)p; p += (size_t)8 * Dd * Dd * 2;
    unsigned short* wfg = (unsigned short*)p; p += (size_t)480 * Dd * 2;
    int* counts = (int*)p; p += (size_t)Ng * 4;
    int* offs   = (int*)p; p += (size_t)(Ng + 1) * 4 + 12;
    int* cursor = (int*)p; p += (size_t)Ng * 4;
    int* eid    = (int*)p; p += (size_t)Eg * 4;

    // ---- merged fp32 -> bf16 conversions ----
    CvtPack cp;
    cp.s[0] = unixe; cp.d[0] = ubf;  cp.n4[0] = Ng * EMBd / 4;
    cp.s[1] = g1W;   cp.d[1] = wg1;  cp.n4[1] = HDd * EMBd / 4;
    cp.s[2] = g2W;   cp.d[2] = wg2;  cp.n4[2] = HDd * HDd / 4;
    cp.s[3] = fcW;   cp.d[3] = wfc;  cp.n4[3] = Dd * HDd / 4;
    cp.s[4] = hidW;  cp.d[4] = whid; cp.n4[4] = 8 * Dd * Dd / 4;
    cp.s[5] = fgW;   cp.d[5] = wfg;  cp.n4[5] = 480 * Dd / 4;
    int total4 = cp.n4[0] + cp.n4[1] + cp.n4[2] + cp.n4[3] + cp.n4[4] + cp.n4[5];
    cvt_all<<<(total4 + 255)/256, 256, 0, stream>>>(cp, total4);

    // ---- image / text branches: BN prep + high-occupancy GEMV ----
    bn_prep<<<(IMGd + 255)/256, 256, 0, stream>>>(swg, swb, swm, swv, sci, shi, IMGd);
    bn_prep<<<(EMBd + 255)/256, 256, 0, stream>>>(btg, btb, btm, btv, sct, sht, EMBd);
    branch_gemv<<<Bg * (Dd / 4), 256, 0, stream>>>(img, swW, swbi, sci, shi, xb, Dd, IMGd);
    branch_gemv<<<Bg * (Dd / 4), 256, 0, stream>>>(ftxt, ftW, ftbi, sct, sht, ftb, Dd, EMBd);

    // ---- CSR by dst ----
    zero_i32<<<(Ng + 255)/256, 256, 0, stream>>>(counts, Ng);
    count_dst<<<(Eg + 255)/256, 256, 0, stream>>>(dst, counts, Eg);
    scan_excl<<<1, 1024, 0, stream>>>(counts, offs, cursor, Ng);
    scatter_edges<<<(Eg + 255)/256, 256, 0, stream>>>(dst, cursor, eid, Eg);

    // ---- GAT layer 1 (256^2 8-phase GEMM) ----
    gemm_bf16_256<<<dim3(HDd/256, Ng/256), 512, 0, stream>>>(ubf, wg1, nullptr, fA, Ng, HDd, EMBd, 0, 1);
    elr_kernel<<<Ng, 256, 0, stream>>>(fA, g1al, g1ar, el, er);
    gat_agg<<<Ng, 256, 0, stream>>>(fA, el, er, src, offs, eid, g1b, fB);

    // ---- GAT layer 2 ----
    gemm_bf16_256<<<dim3(HDd/256, Ng/256), 512, 0, stream>>>(fB, wg2, nullptr, fA, Ng, HDd, HDd, 0, 1);
    elr_kernel<<<Ng, 256, 0, stream>>>(fA, g2al, g2ar, el, er);
    gat_agg<<<Ng, 256, 0, stream>>>(fA, el, er, src, offs, eid, g2b, fB);

    // ---- fc: [6400,2048] -> [6400,512], elu ----
    gemm_bf16_t64<<<dim3(Dd/64, Ng/64), 256, 0, stream>>>(
        fB, wfc, fcb, fC, Ng, Dd, HDd, 1, 1, nullptr, nullptr, nullptr, nullptr);

    // ---- 8 hidden layers, ping-pong fC<->fD; layer 8 fuses node-BN ----
    unsigned short* cur = fC; unsigned short* nxt = fD;
    for (int i = 0; i < 8; ++i) {
        const float* rg = (i == 7) ? bgg : nullptr;
        const float* rb = (i == 7) ? bgb : nullptr;
        const float* rm = (i == 7) ? bgm : nullptr;
        const float* rv = (i == 7) ? bgv : nullptr;
        gemm_bf16_t64<<<dim3(Dd/64, Ng/64), 256, 0, stream>>>(
            cur, whid + (size_t)i * Dd * Dd, hidb + (size_t)i * Dd, nxt, Ng, Dd, Dd, 1, 1,
            rg, rb, rm, rv);
        unsigned short* t = cur; cur = nxt; nxt = t;
    }
    // BN'd result in cur

    // ---- fc_gat -> [6400,480] f32 ----
    gemm_bf16_t64<<<dim3(8, Ng/64), 256, 0, stream>>>(
        cur, wfg, fgb, fE, Ng, 480, Dd, 1, 0, nullptr, nullptr, nullptr, nullptr);

    // ---- mean (pos branch fused) -> hf[64,512] ----
    mean_kernel<<<(Bg*Dd + 255)/256, 256, 0, stream>>>(fE, pos, bbgp, bbbp, bbmp, bbvp, fbW, fbb, hf);

    // ---- final BN + linear -> out[64,2] ----
    final_kernel<<<Bg, 256, 0, stream>>>(xb, hf, ftb, fng, fnb, fnm, fnv, fiW, fib, out);
}

// Round 11
// 693.037 us; speedup vs baseline: 1.0204x; 1.0204x over previous
//
#include <hip/hip_runtime.h>
#include <math.h>

#define Bg   64
#define Mg   100
#define Ng   6400
#define Eg   102400
#define Hh   4
#define Dd   512
#define HDd  2048
#define EMBd 768
#define IMGd 1024
#define EPSc 1e-5f

typedef __bf16 bf16x8 __attribute__((ext_vector_type(8)));
typedef float  f32x4  __attribute__((ext_vector_type(4)));

#define SBAR __builtin_amdgcn_sched_barrier(0)
#define WBAR __builtin_amdgcn_s_barrier()

__device__ __forceinline__ float eluf(float x) { return x > 0.f ? x : expm1f(x); }

__device__ __forceinline__ unsigned short f2bf(float x) {
    unsigned int u = __builtin_bit_cast(unsigned int, x);
    u += 0x7FFFu + ((u >> 16) & 1u);
    return (unsigned short)(u >> 16);
}
__device__ __forceinline__ float bf2f(unsigned short s) {
    return __builtin_bit_cast(float, ((unsigned int)s) << 16);
}
__device__ __forceinline__ float bflo(unsigned int u) {
    return __builtin_bit_cast(float, u << 16);
}
__device__ __forceinline__ float bfhi(unsigned int u) {
    return __builtin_bit_cast(float, u & 0xFFFF0000u);
}

__device__ __forceinline__ void gld16(const void* g, void* l) {
    __builtin_amdgcn_global_load_lds(
        (const __attribute__((address_space(1))) void*)g,
        (__attribute__((address_space(3))) void*)l, 16, 0, 0);
}

// ---------------------------------------------------------------------------
// bf16 MFMA GEMM, 256x256 tile, 8-phase pipeline (T2+T3+T4+T5), R6 sync form.
// Requires M%256==0, N%256==0, K%128==0.  C = act(A[M,K] @ W[N,K]^T + b)
// ---------------------------------------------------------------------------
__global__ __launch_bounds__(512, 2)
void gemm_bf16_256(const unsigned short* __restrict__ A,
                   const unsigned short* __restrict__ W,
                   const float* __restrict__ bias, void* __restrict__ C,
                   int M, int N, int K, int act, int outbf)
{
    __shared__ __align__(16) unsigned short As[2][256 * 64];
    __shared__ __align__(16) unsigned short Bs[2][256 * 64];

    const int tid  = threadIdx.x;
    const int lane = tid & 63, wid = tid >> 6;
    const int wm = wid >> 2, wn = wid & 3;
    const int bm = blockIdx.y * 256, bn = blockIdx.x * 256;
    const int fl = lane & 15;                 // fragment row within 16
    const int fsl = lane >> 4;                // logical 16B slot of fragment

    f32x4 acc[8][4] = {};
    bf16x8 a_[4][2];
    bf16x8 b_[2][2][2];

    const int NT = K >> 6;                    // 64-wide K-tiles (even count)

    const int srow0 = tid >> 3;
    const int scol  = (((tid & 7) ^ ((tid >> 3) & 7)) << 3);
    const unsigned short* pAs = A + (size_t)(bm + srow0) * K + scol;
    const unsigned short* pBs = W + (size_t)(bn + srow0) * K + scol;
    const size_t K64 = (size_t)K * 64, K128 = (size_t)K * 128;

#define STGA(kt, h, d)                                                        \
    do {                                                                      \
        gld16(pAs + (h) * K128 + ((kt) << 6),                                 \
              (char*)As[d] + (h) * 16384 + wid * 1024);                       \
        gld16(pAs + (h) * K128 + K64 + ((kt) << 6),                           \
              (char*)As[d] + (h) * 16384 + 8192 + wid * 1024);                \
    } while (0)
#define STGB(kt, h, d)                                                        \
    do {                                                                      \
        gld16(pBs + (h) * K128 + ((kt) << 6),                                 \
              (char*)Bs[d] + (h) * 16384 + wid * 1024);                       \
        gld16(pBs + (h) * K128 + K64 + ((kt) << 6),                           \
              (char*)Bs[d] + (h) * 16384 + 8192 + wid * 1024);                \
    } while (0)

#define LDA(qm, d)                                                            \
    _Pragma("unroll") for (int i = 0; i < 4; ++i)                             \
    _Pragma("unroll") for (int kk = 0; kk < 2; ++kk) {                        \
        int r_  = wm * 128 + (qm) * 64 + i * 16 + fl;                         \
        int sl_ = ((kk << 2) + fsl) ^ (fl & 7);                               \
        a_[i][kk] = *(const bf16x8*)((const char*)As[d] + r_ * 128 + (sl_ << 4)); \
    }
#define LDB(qn, d)                                                            \
    _Pragma("unroll") for (int j = 0; j < 2; ++j)                             \
    _Pragma("unroll") for (int kk = 0; kk < 2; ++kk) {                        \
        int r_  = wn * 64 + (qn) * 32 + j * 16 + fl;                          \
        int sl_ = ((kk << 2) + fsl) ^ (fl & 7);                               \
        b_[qn][j][kk] = *(const bf16x8*)((const char*)Bs[d] + r_ * 128 + (sl_ << 4)); \
    }
#define PHMM(qm, qn)                                                          \
    do {                                                                      \
        WBAR;                                                                 \
        __builtin_amdgcn_s_setprio(1);                                        \
        _Pragma("unroll") for (int kk = 0; kk < 2; ++kk)                      \
        _Pragma("unroll") for (int i = 0; i < 4; ++i)                         \
        _Pragma("unroll") for (int j = 0; j < 2; ++j)                         \
            acc[(qm) * 4 + i][(qn) * 2 + j] =                                 \
                __builtin_amdgcn_mfma_f32_16x16x32_bf16(                      \
                    a_[i][kk], b_[qn][j][kk],                                 \
                    acc[(qm) * 4 + i][(qn) * 2 + j], 0, 0, 0);                \
        __builtin_amdgcn_s_setprio(0);                                        \
        WBAR;                                                                 \
    } while (0)

    // ---- prologue: B(0), A(0), B(1); drain tile 0, leave B(1) in flight ----
    STGB(0, 0, 0); STGB(0, 1, 0);
    STGA(0, 0, 0); STGA(0, 1, 0);
    STGB(1, 0, 1); STGB(1, 1, 1);
    asm volatile("s_waitcnt vmcnt(4)" ::: "memory");
    WBAR;

    for (int j = 0; j < (NT >> 1); ++j) {
        const int O = 2 * j + 1;
        const int g1 = (2 * j + 2 < NT), g2 = (2 * j + 3 < NT);

        LDA(0, 0); LDB(0, 0);
        STGA(O, 0, 1);
        PHMM(0, 0);

        LDB(1, 0);
        STGA(O, 1, 1);
        PHMM(0, 1);

        LDA(1, 0);
        if (g1) STGB(2 * j + 2, 0, 0);
        PHMM(1, 0);

        if (g1) STGB(2 * j + 2, 1, 0);
        if (g1) { asm volatile("s_waitcnt vmcnt(4)" ::: "memory"); }
        else    { asm volatile("s_waitcnt vmcnt(0)" ::: "memory"); }
        PHMM(1, 1);

        LDA(0, 1); LDB(0, 1);
        if (g1) STGA(2 * j + 2, 0, 0);
        PHMM(0, 0);

        LDB(1, 1);
        if (g1) STGA(2 * j + 2, 1, 0);
        PHMM(0, 1);

        LDA(1, 1);
        if (g2) STGB(2 * j + 3, 0, 1);
        PHMM(1, 0);

        if (g2) STGB(2 * j + 3, 1, 1);
        if (g1) { asm volatile("s_waitcnt vmcnt(4)" ::: "memory"); }
        else    { asm volatile("s_waitcnt vmcnt(0)" ::: "memory"); }
        PHMM(1, 1);
    }

#undef STGA
#undef STGB
#undef LDA
#undef LDB
#undef PHMM

    // ---- epilogue ----
    const int crow0 = bm + wm * 128 + ((lane >> 4) << 2);
    const int ccol0 = bn + wn * 64 + fl;
#pragma unroll
    for (int fr = 0; fr < 8; ++fr) {
#pragma unroll
        for (int fc = 0; fc < 4; ++fc) {
            int col = ccol0 + fc * 16;
            float bv = bias ? bias[col] : 0.f;
#pragma unroll
            for (int rr = 0; rr < 4; ++rr) {
                int row = crow0 + fr * 16 + rr;
                float v = acc[fr][fc][rr] + bv;
                if (act) v = eluf(v);
                if (outbf) ((unsigned short*)C)[(size_t)row * N + col] = f2bf(v);
                else       ((float*)C)[(size_t)row * N + col] = v;
            }
        }
    }
}

// ---------------------------------------------------------------------------
// bf16 MFMA GEMM, 64x64 tile, depth-2 counted-vmcnt pipeline + conflict-free
// LDS swizzle (R9 proven form; R10's K64 variant was null and halved max
// occupancy -> reverted). Optional fused row-BN (p = row%100) after act.
// ---------------------------------------------------------------------------
__global__ __launch_bounds__(256)
void gemm_bf16_t64(const unsigned short* __restrict__ A,
                   const unsigned short* __restrict__ W,
                   const float* __restrict__ bias, void* __restrict__ C,
                   int M, int N, int K, int act, int outbf,
                   const float* __restrict__ rg, const float* __restrict__ rb,
                   const float* __restrict__ rm, const float* __restrict__ rv)
{
    __shared__ __align__(16) unsigned short As[2][64 * 32];
    __shared__ __align__(16) unsigned short Bs[2][64 * 32];
    const int tid  = threadIdx.x;
    const int lane = tid & 63, wid = tid >> 6;
    const int bm = blockIdx.y * 64, bn = blockIdx.x * 64;
    const int wm = (wid >> 1) * 32, wn = (wid & 1) * 32;
    const int lrow = lane >> 2;
    const int lcol = (((lane & 3) ^ ((lane >> 3) & 3)) << 3);   // pre-swizzled

    f32x4 acc[2][2] = {};

    const int ra = wid * 16;
    const unsigned short* gA = A + (size_t)(bm + ra + lrow) * K + lcol;
    int rbn = bn + ra + lrow; if (rbn >= N) rbn = N - 1;
    const unsigned short* gB = W + (size_t)rbn * K + lcol;

    const int frow = lane & 15;
    const int qsw = (((lane >> 4) ^ ((frow >> 1) & 3)) << 3);   // swizzled read slot
    const int nt = K >> 5;

#define STAGE64(t, b)                           \
    do {                                        \
        const int k0_ = (t) << 5;               \
        gld16(gA + k0_, &As[b][ra * 32]);       \
        gld16(gB + k0_, &Bs[b][ra * 32]);       \
    } while (0)

    STAGE64(0, 0);
    if (nt > 1) STAGE64(1, 1);

    for (int t = 0; t < nt; ++t) {
        const int bi = t & 1;
        if (t + 1 < nt) { asm volatile("s_waitcnt vmcnt(2)" ::: "memory"); }
        else            { asm volatile("s_waitcnt vmcnt(0)" ::: "memory"); }
        WBAR;

        bf16x8 af0 = *(const bf16x8*)&As[bi][(wm + frow) * 32 + qsw];
        bf16x8 af1 = *(const bf16x8*)&As[bi][(wm + 16 + frow) * 32 + qsw];
        bf16x8 bf0 = *(const bf16x8*)&Bs[bi][(wn + frow) * 32 + qsw];
        bf16x8 bf1 = *(const bf16x8*)&Bs[bi][(wn + 16 + frow) * 32 + qsw];
        acc[0][0] = __builtin_amdgcn_mfma_f32_16x16x32_bf16(af0, bf0, acc[0][0], 0, 0, 0);
        acc[0][1] = __builtin_amdgcn_mfma_f32_16x16x32_bf16(af0, bf1, acc[0][1], 0, 0, 0);
        acc[1][0] = __builtin_amdgcn_mfma_f32_16x16x32_bf16(af1, bf0, acc[1][0], 0, 0, 0);
        acc[1][1] = __builtin_amdgcn_mfma_f32_16x16x32_bf16(af1, bf1, acc[1][1], 0, 0, 0);

        asm volatile("s_waitcnt lgkmcnt(0)" ::: "memory");
        WBAR;
        if (t + 2 < nt) STAGE64(t + 2, bi);
    }
#undef STAGE64

    const int crow0 = bm + wm + ((lane >> 4) << 2);
    const int ccol0 = bn + wn + (lane & 15);
#pragma unroll
    for (int mi = 0; mi < 2; ++mi) {
#pragma unroll
        for (int ni = 0; ni < 2; ++ni) {
            int col = ccol0 + ni * 16;
            if (col >= N) continue;
            float bv = bias ? bias[col] : 0.f;
#pragma unroll
            for (int r = 0; r < 4; ++r) {
                int row = crow0 + mi * 16 + r;
                float v = acc[mi][ni][r] + bv;
                if (act) v = eluf(v);
                if (rg) {
                    int prow = row % Mg;
                    float sc = rsqrtf(rv[prow] + EPSc) * rg[prow];
                    v = v * sc + (rb[prow] - rm[prow] * sc);
                }
                if (outbf) ((unsigned short*)C)[(size_t)row * N + col] = f2bf(v);
                else       ((float*)C)[(size_t)row * N + col] = v;
            }
        }
    }
}

// ---------------------------------------------------------------------------
// BN scale/shift precompute: sc = g*rsqrt(v+eps), sh = b - m*sc
// ---------------------------------------------------------------------------
__global__ void bn_prep(const float* __restrict__ g, const float* __restrict__ b,
                        const float* __restrict__ m, const float* __restrict__ v,
                        float* __restrict__ sc, float* __restrict__ sh, int K)
{
    int i = blockIdx.x * 256 + threadIdx.x;
    if (i < K) {
        float s = rsqrtf(v[i] + EPSc) * g[i];
        sc[i] = s;
        sh[i] = b[i] - m[i] * s;
    }
}

// ---------------------------------------------------------------------------
// Branch GEMV: Y[64,N] = elu((X*sc+sh) @ Wt^T + bias). One wave per output
// element, 4 outputs (same row) per block -> 64*N/4 blocks (full occupancy).
// Requires K % 256 == 0 (K=1024 img, K=768 text).
// ---------------------------------------------------------------------------
__global__ __launch_bounds__(256)
void branch_gemv(const float* __restrict__ X, const float* __restrict__ Wt,
                 const float* __restrict__ bias,
                 const float* __restrict__ sc, const float* __restrict__ sh,
                 float* __restrict__ Y, int N, int K)
{
    const int wid = threadIdx.x >> 6, lane = threadIdx.x & 63;
    const int nb = N >> 2;
    const int r  = blockIdx.x / nb;
    const int n  = (blockIdx.x % nb) * 4 + wid;
    const float* xp = X + (size_t)r * K;
    const float* wp = Wt + (size_t)n * K;
    float s = 0.f;
    for (int k = lane * 4; k < K; k += 256) {
        float4 x  = *(const float4*)(xp + k);
        float4 w  = *(const float4*)(wp + k);
        float4 cc = *(const float4*)(sc + k);
        float4 hh = *(const float4*)(sh + k);
        s += (x.x * cc.x + hh.x) * w.x + (x.y * cc.y + hh.y) * w.y
           + (x.z * cc.z + hh.z) * w.z + (x.w * cc.w + hh.w) * w.w;
    }
#pragma unroll
    for (int o = 32; o > 0; o >>= 1) s += __shfl_down(s, o, 64);
    if (lane == 0) Y[(size_t)r * N + n] = eluf(s + bias[n]);
}

// ---------------------------------------------------------------------------
// Merged fp32 -> bf16 conversion for 6 arrays (4-wide; all sizes %4 == 0).
// ---------------------------------------------------------------------------
struct CvtPack {
    const float* s[6];
    unsigned short* d[6];
    int n4[6];
};

__global__ void cvt_all(CvtPack p, int total4)
{
    int i = blockIdx.x * 256 + threadIdx.x;
    if (i >= total4) return;
#pragma unroll
    for (int k = 0; k < 6; ++k) {
        if (i < p.n4[k]) {
            float4 v = ((const float4*)p.s[k])[i];
            ushort4 o;
            o.x = f2bf(v.x); o.y = f2bf(v.y); o.z = f2bf(v.z); o.w = f2bf(v.w);
            ((ushort4*)p.d[k])[i] = o;
            return;
        }
        i -= p.n4[k];
    }
}

// ---------------------------------------------------------------------------
// CSR build by dst
// ---------------------------------------------------------------------------
__global__ void zero_i32(int* __restrict__ p, int n)
{
    int i = blockIdx.x * 256 + threadIdx.x;
    if (i < n) p[i] = 0;
}

__global__ void count_dst(const int* __restrict__ dst, int* __restrict__ counts, int E)
{
    int i = blockIdx.x * 256 + threadIdx.x;
    if (i < E) atomicAdd(&counts[dst[i]], 1);
}

__global__ __launch_bounds__(1024)
void scan_excl(const int* __restrict__ counts, int* __restrict__ offs,
               int* __restrict__ cursor, int n)
{
    __shared__ int sm[1024];
    __shared__ int carry;
    if (threadIdx.x == 0) carry = 0;
    __syncthreads();
    for (int base = 0; base < n; base += 1024) {
        int i = base + (int)threadIdx.x;
        int v = (i < n) ? counts[i] : 0;
        sm[threadIdx.x] = v;
        __syncthreads();
        for (int o = 1; o < 1024; o <<= 1) {
            int t = (threadIdx.x >= (unsigned)o) ? sm[threadIdx.x - o] : 0;
            __syncthreads();
            sm[threadIdx.x] += t;
            __syncthreads();
        }
        int incl = sm[threadIdx.x];
        int myc = carry;
        if (i < n) {
            int ex = myc + incl - v;
            offs[i] = ex;
            cursor[i] = ex;
        }
        __syncthreads();
        if (threadIdx.x == 1023) carry = myc + sm[1023];
        __syncthreads();
    }
    if (threadIdx.x == 0) offs[n] = carry;
}

__global__ void scatter_edges(const int* __restrict__ dst, int* __restrict__ cursor,
                              int* __restrict__ eid, int E)
{
    int i = blockIdx.x * 256 + threadIdx.x;
    if (i < E) {
        int p = atomicAdd(&cursor[dst[i]], 1);
        eid[p] = i;
    }
}

// ---------------------------------------------------------------------------
// el/er: one wave per (n,h); lane owns 8 consecutive dims -> one 16B load.
// ---------------------------------------------------------------------------
__global__ __launch_bounds__(256)
void elr_kernel(const unsigned short* __restrict__ Hm, const float* __restrict__ al,
                const float* __restrict__ ar, float* __restrict__ el,
                float* __restrict__ er)
{
    int wid = threadIdx.x >> 6, lane = threadIdx.x & 63;
    int g = (blockIdx.x << 2) + wid;
    int n = g >> 2, h = g & 3;
    const unsigned short* hp = Hm + ((size_t)n << 11) + (h << 9) + (lane << 3);
    const float* alp = al + (h << 9) + (lane << 3);
    const float* arp = ar + (h << 9) + (lane << 3);
    ushort4 x0 = *(const ushort4*)hp;
    ushort4 x1 = *(const ushort4*)(hp + 4);
    float4 l0 = *(const float4*)alp, l1 = *(const float4*)(alp + 4);
    float4 r0 = *(const float4*)arp, r1 = *(const float4*)(arp + 4);
    float a0 = bf2f(x0.x), a1 = bf2f(x0.y), a2 = bf2f(x0.z), a3 = bf2f(x0.w);
    float a4 = bf2f(x1.x), a5 = bf2f(x1.y), a6 = bf2f(x1.z), a7 = bf2f(x1.w);
    float se = a0*l0.x + a1*l0.y + a2*l0.z + a3*l0.w + a4*l1.x + a5*l1.y + a6*l1.z + a7*l1.w;
    float sr = a0*r0.x + a1*r0.y + a2*r0.z + a3*r0.w + a4*r1.x + a5*r1.y + a6*r1.z + a7*r1.w;
#pragma unroll
    for (int o = 32; o > 0; o >>= 1) {
        se += __shfl_down(se, o, 64);
        sr += __shfl_down(sr, o, 64);
    }
    if (lane == 0) { el[g] = se; er[g] = sr; }
}

// ---------------------------------------------------------------------------
// GAT aggregation: one block per dst node. R11: thread owns 8 CONSECUTIVE
// dims [8t, 8t+8) -> ONE 16B load + ONE 16B store per edge (was 2x8B loads,
// 2x8B stores); head = tid>>6. Same edge order per dim -> bit-identical.
// ---------------------------------------------------------------------------
__global__ __launch_bounds__(256)
void gat_agg(const unsigned short* __restrict__ Hm, const float* __restrict__ el,
             const float* __restrict__ er, const int* __restrict__ src,
             const int* __restrict__ offs, const int* __restrict__ eid,
             const float* __restrict__ bias, unsigned short* __restrict__ out)
{
    int n = blockIdx.x;
    int tid = threadIdx.x;
    int beg = offs[n], end = offs[n + 1];
    int deg = end - beg;
    const int d0 = tid << 3;          // dims d0..d0+7 (one 16B chunk)
    const int h  = tid >> 6;          // head of this chunk

    if (deg == 0) {
        ushort4 o0, o1;
        o0.x = f2bf(bias[d0 + 0]); o0.y = f2bf(bias[d0 + 1]);
        o0.z = f2bf(bias[d0 + 2]); o0.w = f2bf(bias[d0 + 3]);
        o1.x = f2bf(bias[d0 + 4]); o1.y = f2bf(bias[d0 + 5]);
        o1.z = f2bf(bias[d0 + 6]); o1.w = f2bf(bias[d0 + 7]);
        *(ushort4*)(out + ((size_t)n << 11) + d0)     = o0;
        *(ushort4*)(out + ((size_t)n << 11) + d0 + 4) = o1;
        return;
    }

    __shared__ float m_sh[4], s_sh[4], al_sh[4];
    __shared__ int   src_sh[128];
    __shared__ float logit_sh[512];
    __shared__ float w_sh[512];

    if (tid < 4) { m_sh[tid] = -INFINITY; s_sh[tid] = 0.f; }
    float acc[8] = {0.f,0.f,0.f,0.f,0.f,0.f,0.f,0.f};
    __syncthreads();

    for (int c0 = 0; c0 < deg; c0 += 128) {
        int cnt = min(128, deg - c0);
        for (int i = tid; i < cnt; i += 256) src_sh[i] = src[eid[beg + c0 + i]];
        __syncthreads();
        for (int idx = tid; idx < (cnt << 2); idx += 256) {
            int i = idx >> 2, hh = idx & 3;
            float x = el[(src_sh[i] << 2) + hh] + er[(n << 2) + hh];
            logit_sh[idx] = x > 0.f ? x : 0.2f * x;
        }
        __syncthreads();
        if (tid < 4) {
            float cm = -INFINITY;
            for (int i = 0; i < cnt; ++i) cm = fmaxf(cm, logit_sh[(i << 2) + tid]);
            float mn = fmaxf(m_sh[tid], cm);
            al_sh[tid] = expf(m_sh[tid] - mn);
            m_sh[tid] = mn;
        }
        __syncthreads();
        for (int idx = tid; idx < (cnt << 2); idx += 256)
            w_sh[idx] = expf(logit_sh[idx] - m_sh[idx & 3]);
        __syncthreads();
        if (tid < 4) {
            float cs = 0.f;
            for (int i = 0; i < cnt; ++i) cs += w_sh[(i << 2) + tid];
            s_sh[tid] = s_sh[tid] * al_sh[tid] + cs;
        }
        float r = al_sh[h];
#pragma unroll
        for (int j = 0; j < 8; ++j) acc[j] *= r;
#pragma unroll 2
        for (int i = 0; i < cnt; ++i) {
            const uint4 v = *(const uint4*)(Hm + ((size_t)src_sh[i] << 11) + d0);
            float w = w_sh[(i << 2) + h];
            acc[0] += w * bflo(v.x); acc[1] += w * bfhi(v.x);
            acc[2] += w * bflo(v.y); acc[3] += w * bfhi(v.y);
            acc[4] += w * bflo(v.z); acc[5] += w * bfhi(v.z);
            acc[6] += w * bflo(v.w); acc[7] += w * bfhi(v.w);
        }
        __syncthreads();
    }

    float is = 1.f / s_sh[h];
    ushort4 o0, o1;
    o0.x = f2bf(acc[0] * is + bias[d0 + 0]);
    o0.y = f2bf(acc[1] * is + bias[d0 + 1]);
    o0.z = f2bf(acc[2] * is + bias[d0 + 2]);
    o0.w = f2bf(acc[3] * is + bias[d0 + 3]);
    o1.x = f2bf(acc[4] * is + bias[d0 + 4]);
    o1.y = f2bf(acc[5] * is + bias[d0 + 5]);
    o1.z = f2bf(acc[6] * is + bias[d0 + 6]);
    o1.w = f2bf(acc[7] * is + bias[d0 + 7]);
    *(ushort4*)(out + ((size_t)n << 11) + d0)     = o0;
    *(ushort4*)(out + ((size_t)n << 11) + d0 + 4) = o1;
}

// ---------------------------------------------------------------------------
// mean over 100 nodes of concat([hg 480, pos-branch 32]) -> hf[64,512].
// pos branch computed inline (p = n%100 = m within a graph).
// ---------------------------------------------------------------------------
__global__ void mean_kernel(const float* __restrict__ hg, const float* __restrict__ pos,
                            const float* __restrict__ bg, const float* __restrict__ bb_,
                            const float* __restrict__ bm_, const float* __restrict__ bv_,
                            const float* __restrict__ W, const float* __restrict__ bias,
                            float* __restrict__ hf)
{
    int i = blockIdx.x * 256 + threadIdx.x;   // < 64*512
    if (i >= Bg * Dd) return;
    int bb = i >> 9, c = i & 511;
    float s = 0.f;
    if (c < 480) {
        const float* p = hg + (size_t)bb * Mg * 480 + c;
        for (int mm = 0; mm < Mg; ++mm) s += p[mm * 480];
    } else {
        int o = c - 480;
        float w0 = W[(o << 2) + 0], w1 = W[(o << 2) + 1];
        float w2 = W[(o << 2) + 2], w3 = W[(o << 2) + 3];
        float bo = bias[o];
        const float* pp = pos + (size_t)bb * Mg * 4;
        for (int mm = 0; mm < Mg; ++mm) {
            float sc = rsqrtf(bv_[mm] + EPSc) * bg[mm];
            float sh = bb_[mm] - bm_[mm] * sc;
            float a = bo + (pp[mm*4+0]*sc+sh)*w0 + (pp[mm*4+1]*sc+sh)*w1
                         + (pp[mm*4+2]*sc+sh)*w2 + (pp[mm*4+3]*sc+sh)*w3;
            s += eluf(a);
        }
    }
    hf[i] = s * 0.01f;
}

__global__ __launch_bounds__(256)
void final_kernel(const float* __restrict__ x, const float* __restrict__ hf,
                  const float* __restrict__ ft, const float* __restrict__ g,
                  const float* __restrict__ b, const float* __restrict__ m,
                  const float* __restrict__ v, const float* __restrict__ W,
                  const float* __restrict__ bias, float* __restrict__ out)
{
    int bb = blockIdx.x;
    int tid = threadIdx.x;
    float a0 = 0.f, a1 = 0.f;
    for (int c = tid; c < 1536; c += 256) {
        float xv = (c < 512) ? x[bb * 512 + c]
                 : (c < 1024) ? hf[bb * 512 + (c - 512)]
                              : ft[bb * 512 + (c - 1024)];
        float z = (xv - m[c]) * rsqrtf(v[c] + EPSc) * g[c] + b[c];
        a0 += z * W[c];
        a1 += z * W[1536 + c];
    }
    __shared__ float r0[256], r1[256];
    r0[tid] = a0; r1[tid] = a1;
    __syncthreads();
    for (int o = 128; o > 0; o >>= 1) {
        if (tid < o) { r0[tid] += r0[tid + o]; r1[tid] += r1[tid + o]; }
        __syncthreads();
    }
    if (tid == 0) {
        out[bb * 2 + 0] = r0[0] + bias[0];
        out[bb * 2 + 1] = r1[0] + bias[1];
    }
}

// ---------------------------------------------------------------------------
extern "C" void kernel_launch(void* const* d_in, const int* in_sizes, int n_in,
                              void* d_out, int out_size, void* d_ws, size_t ws_size,
                              hipStream_t stream)
{
    (void)in_sizes; (void)n_in; (void)out_size; (void)ws_size;

    const float* img   = (const float*)d_in[0];
    const float* ftxt  = (const float*)d_in[1];
    const float* unixe = (const float*)d_in[2];
    const float* pos   = (const float*)d_in[3];
    const int*   src   = (const int*)  d_in[4];
    const int*   dst   = (const int*)  d_in[5];
    const float* g1W   = (const float*)d_in[6];
    const float* g1al  = (const float*)d_in[7];
    const float* g1ar  = (const float*)d_in[8];
    const float* g1b   = (const float*)d_in[9];
    const float* g2W   = (const float*)d_in[10];
    const float* g2al  = (const float*)d_in[11];
    const float* g2ar  = (const float*)d_in[12];
    const float* g2b   = (const float*)d_in[13];
    const float* fcW   = (const float*)d_in[14];
    const float* fcb   = (const float*)d_in[15];
    const float* hidW  = (const float*)d_in[16];
    const float* hidb  = (const float*)d_in[17];
    const float* btg   = (const float*)d_in[18];
    const float* btb   = (const float*)d_in[19];
    const float* btm   = (const float*)d_in[20];
    const float* btv   = (const float*)d_in[21];
    const float* ftW   = (const float*)d_in[22];
    const float* ftbi  = (const float*)d_in[23];
    const float* swg   = (const float*)d_in[24];
    const float* swb   = (const float*)d_in[25];
    const float* swm   = (const float*)d_in[26];
    const float* swv   = (const float*)d_in[27];
    const float* swW   = (const float*)d_in[28];
    const float* swbi  = (const float*)d_in[29];
    const float* bgg   = (const float*)d_in[30];
    const float* bgb   = (const float*)d_in[31];
    const float* bgm   = (const float*)d_in[32];
    const float* bgv   = (const float*)d_in[33];
    const float* fgW   = (const float*)d_in[34];
    const float* fgb   = (const float*)d_in[35];
    const float* bbgp  = (const float*)d_in[36];
    const float* bbbp  = (const float*)d_in[37];
    const float* bbmp  = (const float*)d_in[38];
    const float* bbvp  = (const float*)d_in[39];
    const float* fbW   = (const float*)d_in[40];
    const float* fbb   = (const float*)d_in[41];
    const float* fng   = (const float*)d_in[42];
    const float* fnb   = (const float*)d_in[43];
    const float* fnm   = (const float*)d_in[44];
    const float* fnv   = (const float*)d_in[45];
    const float* fiW   = (const float*)d_in[46];
    const float* fib   = (const float*)d_in[47];
    float* out = (float*)d_out;

    // ---- workspace layout ----
    char* p = (char*)d_ws;
    unsigned short* fA  = (unsigned short*)p; p += (size_t)Ng * HDd * 2;
    unsigned short* fB  = (unsigned short*)p; p += (size_t)Ng * HDd * 2;
    unsigned short* fC  = (unsigned short*)p; p += (size_t)Ng * Dd * 2;
    unsigned short* fD  = (unsigned short*)p; p += (size_t)Ng * Dd * 2;
    float*          fE  = (float*)p;          p += (size_t)Ng * 480 * 4;
    float*          el  = (float*)p;          p += (size_t)Ng * Hh * 4;
    float*          er  = (float*)p;          p += (size_t)Ng * Hh * 4;
    float*          xb  = (float*)p;          p += (size_t)Bg * Dd * 4;
    float*          ftb = (float*)p;          p += (size_t)Bg * Dd * 4;
    float*          hf  = (float*)p;          p += (size_t)Bg * Dd * 4;
    float*          sci = (float*)p;          p += (size_t)IMGd * 4;
    float*          shi = (float*)p;          p += (size_t)IMGd * 4;
    float*          sct = (float*)p;          p += (size_t)EMBd * 4;
    float*          sht = (float*)p;          p += (size_t)EMBd * 4;
    unsigned short* ubf = (unsigned short*)p; p += (size_t)Ng * EMBd * 2;
    unsigned short* wg1 = (unsigned short*)p; p += (size_t)HDd * EMBd * 2;
    unsigned short* wg2 = (unsigned short*)p; p += (size_t)HDd * HDd * 2;
    unsigned short* wfc = (unsigned short*)p; p += (size_t)Dd * HDd * 2;
    unsigned short* whid= (unsigned short*)p; p += (size_t)8 * Dd * Dd * 2;
    unsigned short* wfg = (unsigned short*)p; p += (size_t)480 * Dd * 2;
    int* counts = (int*)p; p += (size_t)Ng * 4;
    int* offs   = (int*)p; p += (size_t)(Ng + 1) * 4 + 12;
    int* cursor = (int*)p; p += (size_t)Ng * 4;
    int* eid    = (int*)p; p += (size_t)Eg * 4;

    // ---- merged fp32 -> bf16 conversions ----
    CvtPack cp;
    cp.s[0] = unixe; cp.d[0] = ubf;  cp.n4[0] = Ng * EMBd / 4;
    cp.s[1] = g1W;   cp.d[1] = wg1;  cp.n4[1] = HDd * EMBd / 4;
    cp.s[2] = g2W;   cp.d[2] = wg2;  cp.n4[2] = HDd * HDd / 4;
    cp.s[3] = fcW;   cp.d[3] = wfc;  cp.n4[3] = Dd * HDd / 4;
    cp.s[4] = hidW;  cp.d[4] = whid; cp.n4[4] = 8 * Dd * Dd / 4;
    cp.s[5] = fgW;   cp.d[5] = wfg;  cp.n4[5] = 480 * Dd / 4;
    int total4 = cp.n4[0] + cp.n4[1] + cp.n4[2] + cp.n4[3] + cp.n4[4] + cp.n4[5];
    cvt_all<<<(total4 + 255)/256, 256, 0, stream>>>(cp, total4);

    // ---- image / text branches: BN prep + high-occupancy GEMV ----
    bn_prep<<<(IMGd + 255)/256, 256, 0, stream>>>(swg, swb, swm, swv, sci, shi, IMGd);
    bn_prep<<<(EMBd + 255)/256, 256, 0, stream>>>(btg, btb, btm, btv, sct, sht, EMBd);
    branch_gemv<<<Bg * (Dd / 4), 256, 0, stream>>>(img, swW, swbi, sci, shi, xb, Dd, IMGd);
    branch_gemv<<<Bg * (Dd / 4), 256, 0, stream>>>(ftxt, ftW, ftbi, sct, sht, ftb, Dd, EMBd);

    // ---- CSR by dst ----
    zero_i32<<<(Ng + 255)/256, 256, 0, stream>>>(counts, Ng);
    count_dst<<<(Eg + 255)/256, 256, 0, stream>>>(dst, counts, Eg);
    scan_excl<<<1, 1024, 0, stream>>>(counts, offs, cursor, Ng);
    scatter_edges<<<(Eg + 255)/256, 256, 0, stream>>>(dst, cursor, eid, Eg);

    // ---- GAT layer 1 (256^2 8-phase GEMM) ----
    gemm_bf16_256<<<dim3(HDd/256, Ng/256), 512, 0, stream>>>(ubf, wg1, nullptr, fA, Ng, HDd, EMBd, 0, 1);
    elr_kernel<<<Ng, 256, 0, stream>>>(fA, g1al, g1ar, el, er);
    gat_agg<<<Ng, 256, 0, stream>>>(fA, el, er, src, offs, eid, g1b, fB);

    // ---- GAT layer 2 ----
    gemm_bf16_256<<<dim3(HDd/256, Ng/256), 512, 0, stream>>>(fB, wg2, nullptr, fA, Ng, HDd, HDd, 0, 1);
    elr_kernel<<<Ng, 256, 0, stream>>>(fA, g2al, g2ar, el, er);
    gat_agg<<<Ng, 256, 0, stream>>>(fA, el, er, src, offs, eid, g2b, fB);

    // ---- fc: [6400,2048] -> [6400,512], elu ----
    gemm_bf16_t64<<<dim3(Dd/64, Ng/64), 256, 0, stream>>>(
        fB, wfc, fcb, fC, Ng, Dd, HDd, 1, 1, nullptr, nullptr, nullptr, nullptr);

    // ---- 8 hidden layers, ping-pong fC<->fD; layer 8 fuses node-BN ----
    unsigned short* cur = fC; unsigned short* nxt = fD;
    for (int i = 0; i < 8; ++i) {
        const float* rg = (i == 7) ? bgg : nullptr;
        const float* rb = (i == 7) ? bgb : nullptr;
        const float* rm = (i == 7) ? bgm : nullptr;
        const float* rv = (i == 7) ? bgv : nullptr;
        gemm_bf16_t64<<<dim3(Dd/64, Ng/64), 256, 0, stream>>>(
            cur, whid + (size_t)i * Dd * Dd, hidb + (size_t)i * Dd, nxt, Ng, Dd, Dd, 1, 1,
            rg, rb, rm, rv);
        unsigned short* t = cur; cur = nxt; nxt = t;
    }
    // BN'd result in cur

    // ---- fc_gat -> [6400,480] f32 ----
    gemm_bf16_t64<<<dim3(8, Ng/64), 256, 0, stream>>>(
        cur, wfg, fgb, fE, Ng, 480, Dd, 1, 0, nullptr, nullptr, nullptr, nullptr);

    // ---- mean (pos branch fused) -> hf[64,512] ----
    mean_kernel<<<(Bg*Dd + 255)/256, 256, 0, stream>>>(fE, pos, bbgp, bbbp, bbmp, bbvp, fbW, fbb, hf);

    // ---- final BN + linear -> out[64,2] ----
    final_kernel<<<Bg, 256, 0, stream>>>(xb, hf, ftb, fng, fnb, fnm, fnv, fiW, fib, out);
}